// Round 2
// baseline (577.570 us; speedup 1.0000x reference)
//
#include <hip/hip_runtime.h>

typedef _Float16 half8 __attribute__((ext_vector_type(8)));
typedef float f32x4 __attribute__((ext_vector_type(4)));

#define B_SZ 64
#define S_SZ 4096
#define H_SZ 256
#define CHUNKS 4
#define SCHUNK (S_SZ / CHUNKS)     // 1024 rows per block
#define WROWS (SCHUNK / 8)         // 128 rows per wave
#define NPAIR (WROWS / 32)         // 4 pair-iterations (32 rows each)

// LDS layout (dynamic shared):
// [0, 131072)        W1 frag-packed f16: chunk(mf,ks,lane) at ((mf*8+ks)*64+lane)*16 B
// [131072, 132096)   biasL f32[256]
// [132096, 133120)   vL    f32[256]
// [133120, 133152)   mArr  f32[8]
// [133152, 133184)   lArr  f32[8]
// epilogue: cspill f32[128][260] = 133120 B overlays [0,133120)
#define LDS_W1_BYTES 131072
#define LDS_BIAS_OFF 131072
#define LDS_V_OFF    132096
#define LDS_M_OFF    133120
#define LDS_L_OFF    133152
#define LDS_TOTAL    133184
#define CSP_STRIDE   260

__device__ __forceinline__ float tanh_fast(float x) {
  // robust: +inf -> 1, -inf -> -1, no NaN
  return 1.f - 2.f / (__expf(2.f * x) + 1.f);
}

// ---------------- kernel 0: bias[b][k] = sum_h final_h[b][h] * W2[k][h] ----------------
__global__ __launch_bounds__(256) void bias_kernel(const float* __restrict__ fh,
                                                   const float* __restrict__ W2,
                                                   float* __restrict__ bias) {
  const int b = blockIdx.x, k = threadIdx.x;
  __shared__ float fsh[H_SZ];
  fsh[k] = fh[b * H_SZ + k];
  __syncthreads();
  const float* wrow = W2 + (size_t)k * H_SZ;
  float s = 0.f;
#pragma unroll 4
  for (int h = 0; h < H_SZ; h += 4) {
    f32x4 w = *(const f32x4*)(wrow + h);
    s += w[0] * fsh[h] + w[1] * fsh[h + 1] + w[2] * fsh[h + 2] + w[3] * fsh[h + 3];
  }
  bias[b * H_SZ + k] = s;
}

// ---------------- kernel 1: fused, wave-private rows, no main-loop barriers ----------------
// grid 256 = 64 b * 4 chunks; block 512 = 8 waves; wave owns 128 S-rows.
// MFMA: D = A(W1) * B(enc^T): A[m=outcol][k=h], B[k=h][n=S-row].
// lane l: r = l&15 (S-row / W1-row in frags), g = l>>4 (k-group / D-row group)
__global__ __launch_bounds__(512, 2) void fused_kernel(const float* __restrict__ enc,
                                                       const float* __restrict__ W1,
                                                       const float* __restrict__ v,
                                                       const float* __restrict__ bias,
                                                       float* __restrict__ pc,   // [256][256]
                                                       float* __restrict__ pl,   // [256]
                                                       float* __restrict__ pm) { // [256]
  extern __shared__ char smem[];
  _Float16* w1l  = (_Float16*)smem;
  float* biasL   = (float*)(smem + LDS_BIAS_OFF);
  float* vL      = (float*)(smem + LDS_V_OFF);
  float* mArr    = (float*)(smem + LDS_M_OFF);
  float* lArr    = (float*)(smem + LDS_L_OFF);

  const int tid = threadIdx.x;
  const int wv = tid >> 6, ln = tid & 63;
  const int r = ln & 15, g = ln >> 4;
  const int b = blockIdx.x >> 2, chunk = blockIdx.x & 3;

  // lane's streaming pointer: row (base + r), h-offset g*8
  const float* pLoad = enc + (((size_t)b * S_SZ + (size_t)chunk * SCHUNK + wv * WROWS + r) * H_SZ + g * 8);

  f32x4 ld[16];  // 16 rows in flight (f32): lane holds 64 h-values of its row slice
  // issue rows 0..15 (stream A of pair 0) BEFORE staging so HBM starts streaming now
#pragma unroll
  for (int ks = 0; ks < 8; ++ks) {
    ld[2 * ks]     = *(const f32x4*)(pLoad + ks * 32);
    ld[2 * ks + 1] = *(const f32x4*)(pLoad + ks * 32 + 4);
  }
  pLoad += 16 * H_SZ;

  // stage W1 (f32 global -> f16 frag-packed LDS); linear conflict-free writes
#pragma unroll
  for (int i = 0; i < 16; ++i) {
    const int q = i * 512 + tid;
    const int lq = q & 63, ksq = (q >> 6) & 7, mfq = q >> 9;
    const float* src = W1 + ((mfq * 16 + (lq & 15)) * H_SZ + ksq * 32 + (lq >> 4) * 8);
    const f32x4 a = *(const f32x4*)src;
    const f32x4 c = *(const f32x4*)(src + 4);
    half8 h;
#pragma unroll
    for (int j = 0; j < 4; ++j) { h[j] = (_Float16)a[j]; h[4 + j] = (_Float16)c[j]; }
    *(half8*)(w1l + (size_t)q * 8) = h;
  }
  if (tid < H_SZ) {
    biasL[tid] = bias[b * H_SZ + tid];
    vL[tid] = v[tid];
  }
  __syncthreads();   // W1L/biasL/vL ready; enc rows 0..15 arrived during staging

  half8 beA[8], beB[8];
  auto cvt = [&](half8* be) {
#pragma unroll
    for (int ks = 0; ks < 8; ++ks) {
      half8 h;
#pragma unroll
      for (int j = 0; j < 4; ++j) { h[j] = (_Float16)ld[2 * ks][j]; h[4 + j] = (_Float16)ld[2 * ks + 1][j]; }
      be[ks] = h;
    }
  };
  auto loads = [&]() {
#pragma unroll
    for (int ks = 0; ks < 8; ++ks) {
      ld[2 * ks]     = *(const f32x4*)(pLoad + ks * 32);
      ld[2 * ks + 1] = *(const f32x4*)(pLoad + ks * 32 + 4);
    }
    pLoad += 16 * H_SZ;
  };

  cvt(beA);      // rows 0
  loads();       // rows 16 (B of pair 0)
  cvt(beB);
  loads();       // rows 32 (A of pair 1) — lands during pair-0 compute

  float m = -1e30f, l = 0.f;
  f32x4 c4[16];  // context: lane's 64 h-values, f32
#pragma unroll
  for (int i = 0; i < 16; ++i) c4[i] = f32x4{0.f, 0.f, 0.f, 0.f};

#pragma unroll 1
  for (int t = 0; t < NPAIR; ++t) {
    float spA = 0.f, spB = 0.f;
#pragma unroll
    for (int mf = 0; mf < 16; ++mf) {
      const f32x4 bias4 = *(const f32x4*)(biasL + mf * 16 + g * 4);  // broadcast read
      const f32x4 v4    = *(const f32x4*)(vL + mf * 16 + g * 4);
      f32x4 dA = bias4, dB = bias4;   // bias folded into accumulator init
#pragma unroll
      for (int ks = 0; ks < 8; ++ks) {
        const half8 wf = *(const half8*)(w1l + ((mf * 8 + ks) * 64 + ln) * 8);
        dA = __builtin_amdgcn_mfma_f32_16x16x32_f16(wf, beA[ks], dA, 0, 0, 0);
        dB = __builtin_amdgcn_mfma_f32_16x16x32_f16(wf, beB[ks], dB, 0, 0, 0);
      }
#pragma unroll
      for (int i = 0; i < 4; ++i) {
        spA += tanh_fast(dA[i]) * v4[i];
        spB += tanh_fast(dB[i]) * v4[i];
      }
    }
    // sum partial scores over the 4 k-groups -> every lane holds score of row (l&15)
    spA += __shfl_xor(spA, 16); spA += __shfl_xor(spA, 32);
    spB += __shfl_xor(spB, 16); spB += __shfl_xor(spB, 32);
    // online softmax over these 32 rows (wave-uniform m, l)
    float mx = fmaxf(spA, spB);
#pragma unroll
    for (int off = 1; off < 16; off <<= 1) mx = fmaxf(mx, __shfl_xor(mx, off));
    const float mnew = fmaxf(m, mx);
    const float wA = __expf(spA - mnew), wB = __expf(spB - mnew);
    float wsum = wA + wB;
#pragma unroll
    for (int off = 1; off < 16; off <<= 1) wsum += __shfl_xor(wsum, off);
    const float rho = __expf(m - mnew);
    l = l * rho + wsum;
    m = mnew;
    // context: lane accumulates its own row's contribution on its h-slice
#pragma unroll
    for (int ks = 0; ks < 8; ++ks) {
#pragma unroll
      for (int j = 0; j < 4; ++j) {
        c4[2 * ks][j]     = c4[2 * ks][j]     * rho + wA * (float)beA[ks][j]     + wB * (float)beB[ks][j];
        c4[2 * ks + 1][j] = c4[2 * ks + 1][j] * rho + wA * (float)beA[ks][4 + j] + wB * (float)beB[ks][4 + j];
      }
    }
    if (t < NPAIR - 1) {
      cvt(beA);                       // A(t+1): arrived during compute
      loads();                        // B(t+1)
      cvt(beB);                       // short exposed wait (~1 HBM latency)
      if (t < NPAIR - 2) loads();     // A(t+2)
    }
  }

  // ---- epilogue: merge 8 waves via LDS (reuse retired W1 region) ----
  __syncthreads();                    // all waves done reading w1l/biasL/vL
  if (ln == 0) { mArr[wv] = m; lArr[wv] = l; }
  __syncthreads();
  float M = mArr[0];
#pragma unroll
  for (int w = 1; w < 8; ++w) M = fmaxf(M, mArr[w]);
  const float scale = __expf(m - M);
  float* cs = (float*)smem;
  float* crow = cs + (wv * 16 + r) * CSP_STRIDE + g * 8;
#pragma unroll
  for (int ks = 0; ks < 8; ++ks) {
    *(f32x4*)(crow + ks * 32)     = c4[2 * ks] * scale;
    *(f32x4*)(crow + ks * 32 + 4) = c4[2 * ks + 1] * scale;
  }
  __syncthreads();
  if (tid < H_SZ) {
    float s = 0.f;
#pragma unroll 8
    for (int rr = 0; rr < 128; ++rr) s += cs[rr * CSP_STRIDE + tid];
    pc[(size_t)blockIdx.x * H_SZ + tid] = s;
  }
  if (tid == 0) {
    float L = 0.f;
#pragma unroll
    for (int w = 0; w < 8; ++w) L += __expf(mArr[w] - M) * lArr[w];
    pl[blockIdx.x] = L;
    pm[blockIdx.x] = M;
  }
}

// ---------------- kernel 2: merge 4 chunk partials per batch ----------------
__global__ __launch_bounds__(256) void combine_kernel(const float* __restrict__ pc,
                                                      const float* __restrict__ pl,
                                                      const float* __restrict__ pm,
                                                      float* __restrict__ out) {
  const int b = blockIdx.x, h = threadIdx.x;
  float M = -1e30f;
#pragma unroll
  for (int j = 0; j < CHUNKS; ++j) M = fmaxf(M, pm[b * CHUNKS + j]);
  float L = 0.f, s = 0.f;
#pragma unroll
  for (int j = 0; j < CHUNKS; ++j) {
    const float e = __expf(pm[b * CHUNKS + j] - M);
    L += pl[b * CHUNKS + j] * e;
    s += e * pc[(size_t)(b * CHUNKS + j) * H_SZ + h];
  }
  out[b * H_SZ + h] = s / L;
}

extern "C" void kernel_launch(void* const* d_in, const int* in_sizes, int n_in,
                              void* d_out, int out_size, void* d_ws, size_t ws_size,
                              hipStream_t stream) {
  const float* enc = (const float*)d_in[0];  // [64,4096,256]
  const float* fh  = (const float*)d_in[1];  // [64,256]
  const float* W1  = (const float*)d_in[2];  // [256,256]
  const float* W2  = (const float*)d_in[3];  // [256,256]
  const float* v   = (const float*)d_in[4];  // [256]
  float* out = (float*)d_out;                // [64,256]

  float* ws   = (float*)d_ws;
  float* bias = ws;                           // 64*256
  float* pc   = ws + B_SZ * H_SZ;             // 256*256
  float* pl   = pc + B_SZ * CHUNKS * H_SZ;    // 256
  float* pm   = pl + B_SZ * CHUNKS;           // 256

  bias_kernel<<<B_SZ, H_SZ, 0, stream>>>(fh, W2, bias);
  fused_kernel<<<B_SZ * CHUNKS, 512, LDS_TOTAL, stream>>>(enc, W1, v, bias, pc, pl, pm);
  combine_kernel<<<B_SZ, H_SZ, 0, stream>>>(pc, pl, pm, out);
}

// Round 3
// 392.064 us; speedup vs baseline: 1.4732x; 1.4732x over previous
//
#include <hip/hip_runtime.h>

typedef _Float16 half8  __attribute__((ext_vector_type(8)));
typedef _Float16 half4_t __attribute__((ext_vector_type(4)));
typedef float    f32x4  __attribute__((ext_vector_type(4)));

#define B_SZ    64
#define S_SZ    4096
#define H_SZ    256
#define CHUNKS  8
#define SCHUNK  512
#define TILE_R  64
#define NTILES  (SCHUNK / TILE_R)   // 8
#define PAD_H   264                 // stride 132 words == 4 mod 32 banks

__device__ __forceinline__ float tanh_fast(float x) {
  // robust: +inf -> 1, -inf -> -1, no NaN
  return 1.f - 2.f / (__expf(2.f * x) + 1.f);
}

// ---------------- kernel 0: bias[b][k] = sum_h final_h[b][h] * W2[k][h] ----------------
__global__ __launch_bounds__(256) void bias_kernel(const float* __restrict__ fh,
                                                   const float* __restrict__ W2,
                                                   float* __restrict__ bias) {
  const int b = blockIdx.x, k = threadIdx.x;
  __shared__ float fsh[H_SZ];
  fsh[k] = fh[b * H_SZ + k];
  __syncthreads();
  const float* wrow = W2 + (size_t)k * H_SZ;
  float s = 0.f;
#pragma unroll 4
  for (int h = 0; h < H_SZ; h += 4) {
    f32x4 w = *(const f32x4*)(wrow + h);
    s += w[0] * fsh[h] + w[1] * fsh[h + 1] + w[2] * fsh[h + 2] + w[3] * fsh[h + 3];
  }
  bias[b * H_SZ + k] = s;
}

// ---------------- kernel 1: fused; no-max softmax (scores bounded by sum|v| ~ 13) ----------
// grid 512 = 64 b * 8 chunks; block 512 = 8 waves. Wave w owns proj cols [32w, 32w+32).
__global__ __launch_bounds__(512, 4) void fused_kernel(const float* __restrict__ enc,
                                                       const float* __restrict__ W1,
                                                       const float* __restrict__ v,
                                                       const float* __restrict__ bias,
                                                       float* __restrict__ pc,   // [512][256]
                                                       float* __restrict__ pl) { // [512]
  __shared__ _Float16 As[2][TILE_R][PAD_H] __attribute__((aligned(16)));  // 67.5 KB
  __shared__ float spartT[TILE_R][12];   // transposed score partials, 16B-aligned rows
  __shared__ float cpart[8][H_SZ];       // epilogue context merge
  __shared__ float lArr[8];

  const int tid  = threadIdx.x;
  const int wave = tid >> 6;
  const int lane = tid & 63;
  const int nlo  = lane & 15;
  const int g    = lane >> 4;
  const int khi  = g * 8;
  const int b     = blockIdx.x >> 3;
  const int chunk = blockIdx.x & 7;
  const size_t encBase = ((size_t)b * S_SZ + (size_t)chunk * SCHUNK) * H_SZ;

  // ---- W1 fragments in registers (verified layout from r1): B[k=h][n=col]
  half8 wf[2][8];
#pragma unroll
  for (int cf = 0; cf < 2; ++cf) {
    const int n = wave * 32 + cf * 16 + nlo;
    const float* wrow = W1 + (size_t)n * H_SZ + khi;
#pragma unroll
    for (int ks = 0; ks < 8; ++ks) {
      f32x4 w0 = *(const f32x4*)(wrow + ks * 32);
      f32x4 w1 = *(const f32x4*)(wrow + ks * 32 + 4);
      half8 h;
#pragma unroll
      for (int j = 0; j < 4; ++j) { h[j] = (_Float16)w0[j]; h[4 + j] = (_Float16)w1[j]; }
      wf[cf][ks] = h;
    }
  }
  const int n0c = wave * 32 + nlo;
  const float vv0 = v[n0c],               vv1 = v[n0c + 16];
  const float bv0 = bias[b * H_SZ + n0c], bv1 = bias[b * H_SZ + n0c + 16];

  float l_acc = 0.f;
  float c0 = 0.f, c1 = 0.f, c2 = 0.f, c3 = 0.f;  // context h-slice: h = 4*lane..+3

  // prologue: loads for tile 0 (8 float4/thread = 64 rows x 256 f32, fully linear)
  f32x4 ld[8];
  {
    const float* src = enc + encBase + (size_t)tid * 4;
#pragma unroll
    for (int i = 0; i < 8; ++i) ld[i] = *(const f32x4*)(src + i * 2048);
  }

#pragma unroll 2
  for (int t = 0; t < NTILES; ++t) {
    const int p = t & 1;
    // stage regs -> LDS (f32 -> f16 RNE), linear layout
#pragma unroll
    for (int i = 0; i < 8; ++i) {
      const int f4 = tid + i * 512;
      const int r = f4 >> 6, hq = (f4 & 63) * 4;
      half4_t hv;
      hv[0] = (_Float16)ld[i][0]; hv[1] = (_Float16)ld[i][1];
      hv[2] = (_Float16)ld[i][2]; hv[3] = (_Float16)ld[i][3];
      *(half4_t*)&As[p][r][hq] = hv;
    }
    // prefetch next tile (in flight across barrier + whole compute phase)
    if (t < NTILES - 1) {
      const float* src = enc + encBase + (size_t)(t + 1) * TILE_R * H_SZ + (size_t)tid * 4;
#pragma unroll
      for (int i = 0; i < 8; ++i) ld[i] = *(const f32x4*)(src + i * 2048);
    }
    __syncthreads();   // As[p] ready

    // ---- MFMA: proj tile [64 x 32(this wave)] -> scores
#pragma unroll
    for (int rf = 0; rf < 4; ++rf) {
      f32x4 d0 = {0.f, 0.f, 0.f, 0.f}, d1 = {0.f, 0.f, 0.f, 0.f};
#pragma unroll
      for (int ks = 0; ks < 8; ++ks) {
        half8 a = *(const half8*)&As[p][rf * 16 + nlo][ks * 32 + khi];
        d0 = __builtin_amdgcn_mfma_f32_16x16x32_f16(a, wf[0][ks], d0, 0, 0, 0);
        d1 = __builtin_amdgcn_mfma_f32_16x16x32_f16(a, wf[1][ks], d1, 0, 0, 0);
      }
      f32x4 s4;
#pragma unroll
      for (int i = 0; i < 4; ++i)
        s4[i] = tanh_fast(d0[i] + bv0) * vv0 + tanh_fast(d1[i] + bv1) * vv1;
      // reduce over the 16 cols spread across lanes (nlo)
#pragma unroll
      for (int off = 1; off < 16; off <<= 1) {
        s4[0] += __shfl_xor(s4[0], off);
        s4[1] += __shfl_xor(s4[1], off);
        s4[2] += __shfl_xor(s4[2], off);
        s4[3] += __shfl_xor(s4[3], off);
      }
      if (nlo == 0) {  // lanes 0,16,32,48: rows rf*16 + g*4 + i, col-slice partial for this wave
#pragma unroll
        for (int i = 0; i < 4; ++i) spartT[rf * 16 + g * 4 + i][wave] = s4[i];
      }
    }
    __syncthreads();   // spartT complete

    // ---- weights + context: wave handles rows [8w, 8w+8); all lanes redundant weights
#pragma unroll
    for (int rr = 0; rr < 8; ++rr) {
      const int r = wave * 8 + rr;
      const f32x4 q0 = *(const f32x4*)&spartT[r][0];   // broadcast reads
      const f32x4 q1 = *(const f32x4*)&spartT[r][4];
      const float u = __expf(q0[0] + q0[1] + q0[2] + q0[3] + q1[0] + q1[1] + q1[2] + q1[3]);
      l_acc += u;
      half4_t a = *(const half4_t*)&As[p][r][lane * 4];
      c0 += u * (float)a[0];
      c1 += u * (float)a[1];
      c2 += u * (float)a[2];
      c3 += u * (float)a[3];
    }
    // no barrier: next staging writes As[p^1]; spartT(t+1) writes occur after barrier1(t+1)
  }

  // ---- epilogue: merge 8 waves
  {
    f32x4 cv; cv[0] = c0; cv[1] = c1; cv[2] = c2; cv[3] = c3;
    *(f32x4*)&cpart[wave][lane * 4] = cv;
  }
  if (lane == 0) lArr[wave] = l_acc;
  __syncthreads();
  if (tid < H_SZ) {
    float s = 0.f;
#pragma unroll
    for (int w = 0; w < 8; ++w) s += cpart[w][tid];
    pc[(size_t)blockIdx.x * H_SZ + tid] = s;
  }
  if (tid == 0) {
    float L = 0.f;
#pragma unroll
    for (int w = 0; w < 8; ++w) L += lArr[w];
    pl[blockIdx.x] = L;
  }
}

// ---------------- kernel 2: merge 8 chunk partials per batch (plain sums, no max) --------
__global__ __launch_bounds__(256) void combine_kernel(const float* __restrict__ pc,
                                                      const float* __restrict__ pl,
                                                      float* __restrict__ out) {
  const int b = blockIdx.x, h = threadIdx.x;
  float L = 0.f, s = 0.f;
#pragma unroll
  for (int j = 0; j < CHUNKS; ++j) {
    L += pl[b * CHUNKS + j];
    s += pc[(size_t)(b * CHUNKS + j) * H_SZ + h];
  }
  out[b * H_SZ + h] = s / L;
}

extern "C" void kernel_launch(void* const* d_in, const int* in_sizes, int n_in,
                              void* d_out, int out_size, void* d_ws, size_t ws_size,
                              hipStream_t stream) {
  const float* enc = (const float*)d_in[0];  // [64,4096,256]
  const float* fh  = (const float*)d_in[1];  // [64,256]
  const float* W1  = (const float*)d_in[2];  // [256,256]
  const float* W2  = (const float*)d_in[3];  // [256,256]
  const float* v   = (const float*)d_in[4];  // [256]
  float* out = (float*)d_out;                // [64,256]

  float* ws   = (float*)d_ws;
  float* bias = ws;                          // 64*256
  float* pc   = ws + B_SZ * H_SZ;            // 512*256
  float* pl   = pc + B_SZ * CHUNKS * H_SZ;   // 512

  bias_kernel<<<B_SZ, H_SZ, 0, stream>>>(fh, W2, bias);
  fused_kernel<<<B_SZ * CHUNKS, 512, 0, stream>>>(enc, W1, v, bias, pc, pl);
  combine_kernel<<<B_SZ, H_SZ, 0, stream>>>(pc, pl, out);
}

// Round 4
// 102.630 us; speedup vs baseline: 5.6277x; 3.8202x over previous
//
#include <hip/hip_runtime.h>

typedef _Float16 half8  __attribute__((ext_vector_type(8)));
typedef _Float16 half4_t __attribute__((ext_vector_type(4)));
typedef float    f32x4  __attribute__((ext_vector_type(4)));

#define B_SZ    64
#define S_SZ    4096
#define H_SZ    256
#define CHUNKS  8
#define SCHUNK  512
#define TILE_R  64
#define NTILES  (SCHUNK / TILE_R)   // 8
#define PAD_H   264                 // row stride 132 words; b128 reads are slot-balanced

__device__ __forceinline__ float tanh_fast(float x) {
  // 1 - 2/(e^{2x}+1); rcpf: +inf -> 1, -inf -> -1, no NaN, ~1ulp err (<< f16 noise)
  return 1.f - 2.f * __builtin_amdgcn_rcpf(__expf(2.f * x) + 1.f);
}

// LDS-visibility barrier that does NOT drain vmcnt: global prefetch stays in flight.
__device__ __forceinline__ void lds_barrier() {
  asm volatile("s_waitcnt lgkmcnt(0)" ::: "memory");
  __builtin_amdgcn_s_barrier();
}

// ---------------- kernel 0: bias[b][k] = sum_h final_h[b][h] * W2[k][h] ----------------
__global__ __launch_bounds__(256) void bias_kernel(const float* __restrict__ fh,
                                                   const float* __restrict__ W2,
                                                   float* __restrict__ bias) {
  const int b = blockIdx.x, k = threadIdx.x;
  __shared__ float fsh[H_SZ];
  fsh[k] = fh[b * H_SZ + k];
  __syncthreads();
  const float* wrow = W2 + (size_t)k * H_SZ;
  float s = 0.f;
#pragma unroll 4
  for (int h = 0; h < H_SZ; h += 4) {
    f32x4 w = *(const f32x4*)(wrow + h);
    s += w[0] * fsh[h] + w[1] * fsh[h + 1] + w[2] * fsh[h + 2] + w[3] * fsh[h + 3];
  }
  bias[b * H_SZ + k] = s;
}

// ---------------- kernel 1: fused; no-max softmax (|score| <= sum|v| ~ 13) ----------------
// grid 512 = 64 b * 8 chunks; block 512 = 8 waves. Wave w owns proj cols [32w, 32w+32).
__global__ __launch_bounds__(512, 2) void fused_kernel(const float* __restrict__ enc,
                                                       const float* __restrict__ W1,
                                                       const float* __restrict__ v,
                                                       const float* __restrict__ bias,
                                                       float* __restrict__ pc,   // [512][256]
                                                       float* __restrict__ pl) { // [512]
  __shared__ _Float16 As[2][TILE_R][PAD_H] __attribute__((aligned(16)));  // 66 KB
  __shared__ float spartT[TILE_R][12];   // transposed score partials
  __shared__ float cpart[8][H_SZ];       // epilogue context merge
  __shared__ float lArr[8];

  const int tid  = threadIdx.x;
  const int wave = tid >> 6;
  const int lane = tid & 63;
  const int nlo  = lane & 15;
  const int g    = lane >> 4;
  const int khi  = g * 8;
  const int b     = blockIdx.x >> 3;
  const int chunk = blockIdx.x & 7;
  const size_t encBase = ((size_t)b * S_SZ + (size_t)chunk * SCHUNK) * H_SZ;

  // ---- W1 fragments in registers: B[k=h][n=col]; lane l holds col wave*32+cf*16+nlo, k=khi+j
  half8 wf[2][8];
#pragma unroll
  for (int cf = 0; cf < 2; ++cf) {
    const int n = wave * 32 + cf * 16 + nlo;
    const float* wrow = W1 + (size_t)n * H_SZ + khi;
#pragma unroll
    for (int ks = 0; ks < 8; ++ks) {
      f32x4 w0 = *(const f32x4*)(wrow + ks * 32);
      f32x4 w1 = *(const f32x4*)(wrow + ks * 32 + 4);
      half8 h;
#pragma unroll
      for (int j = 0; j < 4; ++j) { h[j] = (_Float16)w0[j]; h[4 + j] = (_Float16)w1[j]; }
      wf[cf][ks] = h;
    }
  }
  const int n0c = wave * 32 + nlo;
  const float vv0 = v[n0c],               vv1 = v[n0c + 16];
  const float bv0 = bias[b * H_SZ + n0c], bv1 = bias[b * H_SZ + n0c + 16];

  float l_acc = 0.f;
  float c0 = 0.f, c1 = 0.f, c2 = 0.f, c3 = 0.f;  // context h-slice: h = 4*lane..+3

  // prologue: loads for tile 0
  f32x4 ld[8];
  {
    const float* src = enc + encBase + (size_t)tid * 4;
#pragma unroll
    for (int i = 0; i < 8; ++i) ld[i] = *(const f32x4*)(src + i * 2048);
  }

#pragma unroll 1
  for (int t = 0; t < NTILES; ++t) {
    const int p = t & 1;
    // stage regs -> LDS (f32 -> f16 RNE); compiler inserts vmcnt waits on ld here
#pragma unroll
    for (int i = 0; i < 8; ++i) {
      const int f4 = tid + i * 512;
      const int r = f4 >> 6, hq = (f4 & 63) * 4;
      half4_t hv;
      hv[0] = (_Float16)ld[i][0]; hv[1] = (_Float16)ld[i][1];
      hv[2] = (_Float16)ld[i][2]; hv[3] = (_Float16)ld[i][3];
      *(half4_t*)&As[p][r][hq] = hv;
    }
    lds_barrier();   // As[p] visible; vmcnt NOT drained

    // prefetch next tile NOW: stays in flight until stage(t+1) (barriers don't drain vmcnt)
    if (t < NTILES - 1) {
      const float* src = enc + encBase + (size_t)(t + 1) * TILE_R * H_SZ + (size_t)tid * 4;
#pragma unroll
      for (int i = 0; i < 8; ++i) ld[i] = *(const f32x4*)(src + i * 2048);
    }

    // ---- MFMA: proj tile [64 x 32(this wave)] -> score partials
#pragma unroll
    for (int rf = 0; rf < 4; ++rf) {
      f32x4 d0 = {0.f, 0.f, 0.f, 0.f}, d1 = {0.f, 0.f, 0.f, 0.f};
#pragma unroll
      for (int ks = 0; ks < 8; ++ks) {
        half8 a = *(const half8*)&As[p][rf * 16 + nlo][ks * 32 + khi];
        d0 = __builtin_amdgcn_mfma_f32_16x16x32_f16(a, wf[0][ks], d0, 0, 0, 0);
        d1 = __builtin_amdgcn_mfma_f32_16x16x32_f16(a, wf[1][ks], d1, 0, 0, 0);
      }
      f32x4 s4;
#pragma unroll
      for (int i = 0; i < 4; ++i)
        s4[i] = tanh_fast(d0[i] + bv0) * vv0 + tanh_fast(d1[i] + bv1) * vv1;
#pragma unroll
      for (int off = 1; off < 16; off <<= 1) {
        s4[0] += __shfl_xor(s4[0], off);
        s4[1] += __shfl_xor(s4[1], off);
        s4[2] += __shfl_xor(s4[2], off);
        s4[3] += __shfl_xor(s4[3], off);
      }
      if (nlo == 0) {  // lanes 0,16,32,48: rows rf*16 + g*4 + i
#pragma unroll
        for (int i = 0; i < 4; ++i) spartT[rf * 16 + g * 4 + i][wave] = s4[i];
      }
    }
    lds_barrier();   // spartT visible; prefetch still in flight

    // ---- weights + context: wave handles rows [8w, 8w+8); redundant weights on all lanes
#pragma unroll
    for (int rr = 0; rr < 8; ++rr) {
      const int r = wave * 8 + rr;
      const f32x4 q0 = *(const f32x4*)&spartT[r][0];   // broadcast reads
      const f32x4 q1 = *(const f32x4*)&spartT[r][4];
      const float u = __expf(q0[0] + q0[1] + q0[2] + q0[3] + q1[0] + q1[1] + q1[2] + q1[3]);
      l_acc += u;
      half4_t a = *(const half4_t*)&As[p][r][lane * 4];
      c0 += u * (float)a[0];
      c1 += u * (float)a[1];
      c2 += u * (float)a[2];
      c3 += u * (float)a[3];
    }
    // no barrier: stage(t+1) writes As[p^1] (disjoint); spartT next written after barrier1(t+1)
  }

  // ---- epilogue: merge 8 waves
  {
    f32x4 cv; cv[0] = c0; cv[1] = c1; cv[2] = c2; cv[3] = c3;
    *(f32x4*)&cpart[wave][lane * 4] = cv;
  }
  if (lane == 0) lArr[wave] = l_acc;
  __syncthreads();
  if (tid < H_SZ) {
    float s = 0.f;
#pragma unroll
    for (int w = 0; w < 8; ++w) s += cpart[w][tid];
    pc[(size_t)blockIdx.x * H_SZ + tid] = s;
  }
  if (tid == 0) {
    float L = 0.f;
#pragma unroll
    for (int w = 0; w < 8; ++w) L += lArr[w];
    pl[blockIdx.x] = L;
  }
}

// ---------------- kernel 2: merge 8 chunk partials per batch (plain sums) ----------------
__global__ __launch_bounds__(256) void combine_kernel(const float* __restrict__ pc,
                                                      const float* __restrict__ pl,
                                                      float* __restrict__ out) {
  const int b = blockIdx.x, h = threadIdx.x;
  float L = 0.f, s = 0.f;
#pragma unroll
  for (int j = 0; j < CHUNKS; ++j) {
    L += pl[b * CHUNKS + j];
    s += pc[(size_t)(b * CHUNKS + j) * H_SZ + h];
  }
  out[b * H_SZ + h] = s / L;
}

extern "C" void kernel_launch(void* const* d_in, const int* in_sizes, int n_in,
                              void* d_out, int out_size, void* d_ws, size_t ws_size,
                              hipStream_t stream) {
  const float* enc = (const float*)d_in[0];  // [64,4096,256]
  const float* fh  = (const float*)d_in[1];  // [64,256]
  const float* W1  = (const float*)d_in[2];  // [256,256]
  const float* W2  = (const float*)d_in[3];  // [256,256]
  const float* v   = (const float*)d_in[4];  // [256]
  float* out = (float*)d_out;                // [64,256]

  float* ws   = (float*)d_ws;
  float* bias = ws;                          // 64*256
  float* pc   = ws + B_SZ * H_SZ;            // 512*256
  float* pl   = pc + B_SZ * CHUNKS * H_SZ;   // 512

  bias_kernel<<<B_SZ, H_SZ, 0, stream>>>(fh, W2, bias);
  fused_kernel<<<B_SZ * CHUNKS, 512, 0, stream>>>(enc, W1, v, bias, pc, pl);
  combine_kernel<<<B_SZ, H_SZ, 0, stream>>>(pc, pl, out);
}

// Round 6
// 90.649 us; speedup vs baseline: 6.3715x; 1.1322x over previous
//
#include <hip/hip_runtime.h>

typedef _Float16 half8  __attribute__((ext_vector_type(8)));
typedef _Float16 half4_t __attribute__((ext_vector_type(4)));
typedef float    f32x4  __attribute__((ext_vector_type(4)));

#define B_SZ    64
#define S_SZ    4096
#define H_SZ    256
#define CHUNKS  8
#define SCHUNK  512
#define TILE_R  64
#define NTILES  (SCHUNK / TILE_R)   // 8
#define PAD_H   264                 // row stride 132 words; frag b128 reads conflict-free

__device__ __forceinline__ float tanh_fast(float x) {
  // 1 - 2/(e^{2x}+1); rcpf: +inf -> 1, -inf -> -1, no NaN
  return 1.f - 2.f * __builtin_amdgcn_rcpf(__expf(2.f * x) + 1.f);
}

// LDS-visibility barrier that does NOT drain vmcnt: global prefetch stays in flight.
__device__ __forceinline__ void lds_barrier() {
  asm volatile("s_waitcnt lgkmcnt(0)" ::: "memory");
  __builtin_amdgcn_s_barrier();
}

// x += (value of lane i+N within the 16-lane row), zero past row end (bound_ctrl).
// After shl8,shl4,shl2,shl1: lane 0 of each row holds the 16-lane sum.
template<int CTRL>
__device__ __forceinline__ float dpp_add_shl(float x) {
  int s = __builtin_amdgcn_update_dpp(0, __builtin_bit_cast(int, x), CTRL, 0xf, 0xf, true);
  return x + __builtin_bit_cast(float, s);
}
__device__ __forceinline__ float row_reduce16(float x) {
  x = dpp_add_shl<0x108>(x);  // row_shl:8
  x = dpp_add_shl<0x104>(x);  // row_shl:4
  x = dpp_add_shl<0x102>(x);  // row_shl:2
  x = dpp_add_shl<0x101>(x);  // row_shl:1
  return x;
}

// ---------------- kernel 0: bias[b][k] = sum_h final_h[b][h] * W2[k][h] ----------------
__global__ __launch_bounds__(256) void bias_kernel(const float* __restrict__ fh,
                                                   const float* __restrict__ W2,
                                                   float* __restrict__ bias) {
  const int b = blockIdx.x, k = threadIdx.x;
  __shared__ float fsh[H_SZ];
  fsh[k] = fh[b * H_SZ + k];
  __syncthreads();
  const float* wrow = W2 + (size_t)k * H_SZ;
  float s = 0.f;
#pragma unroll 4
  for (int h = 0; h < H_SZ; h += 4) {
    f32x4 w = *(const f32x4*)(wrow + h);
    s += w[0] * fsh[h] + w[1] * fsh[h + 1] + w[2] * fsh[h + 2] + w[3] * fsh[h + 3];
  }
  bias[b * H_SZ + k] = s;
}

// ---------------- kernel 1: fused; no-max softmax (|score| <= sum|v| ~ 13) ----------------
// grid 512 = 64 b * 8 chunks; block 512 = 8 waves. Wave w owns proj cols [32w, 32w+32).
__global__ __launch_bounds__(512, 2) void fused_kernel(const float* __restrict__ enc,
                                                       const float* __restrict__ W1,
                                                       const float* __restrict__ v,
                                                       const float* __restrict__ bias,
                                                       float* __restrict__ pc,   // [512][256]
                                                       float* __restrict__ pl) { // [512]
  __shared__ _Float16 As[2][TILE_R][PAD_H] __attribute__((aligned(16)));  // 66 KB
  __shared__ float spartT[TILE_R][12];   // transposed score partials
  __shared__ float cpart[8][H_SZ];       // epilogue context merge
  __shared__ float lArr[8];

  const int tid  = threadIdx.x;
  const int wave = tid >> 6;
  const int lane = tid & 63;
  const int nlo  = lane & 15;
  const int g    = lane >> 4;
  const int khi  = g * 8;
  const int b     = blockIdx.x >> 3;
  const int chunk = blockIdx.x & 7;
  const size_t encBase = ((size_t)b * S_SZ + (size_t)chunk * SCHUNK) * H_SZ;

  // prologue: issue tile-0 loads FIRST (critical stream), then W1 fragment setup
  f32x4 ld[8];
  {
    const float* src = enc + encBase + (size_t)tid * 4;
#pragma unroll
    for (int i = 0; i < 8; ++i) ld[i] = *(const f32x4*)(src + i * 2048);
  }

  // ---- W1 fragments in registers: B[k=h][n=col]; lane l holds col wave*32+cf*16+nlo
  half8 wf[2][8];
#pragma unroll
  for (int cf = 0; cf < 2; ++cf) {
    const int n = wave * 32 + cf * 16 + nlo;
    const float* wrow = W1 + (size_t)n * H_SZ + khi;
#pragma unroll
    for (int ks = 0; ks < 8; ++ks) {
      f32x4 w0 = *(const f32x4*)(wrow + ks * 32);
      f32x4 w1 = *(const f32x4*)(wrow + ks * 32 + 4);
      half8 h;
#pragma unroll
      for (int j = 0; j < 4; ++j) { h[j] = (_Float16)w0[j]; h[4 + j] = (_Float16)w1[j]; }
      wf[cf][ks] = h;
    }
  }
  const int n0c = wave * 32 + nlo;
  const float vv0 = v[n0c],               vv1 = v[n0c + 16];
  const float bv0 = bias[b * H_SZ + n0c], bv1 = bias[b * H_SZ + n0c + 16];

  float l_acc = 0.f;
  float c0 = 0.f, c1 = 0.f, c2 = 0.f, c3 = 0.f;  // context h-slice: h = 4*lane..+3

#pragma unroll 1
  for (int t = 0; t < NTILES; ++t) {
    const int p = t & 1;
    const bool pf = (t < NTILES - 1);
    const float* srcN = enc + encBase + (size_t)(t + 1) * TILE_R * H_SZ + (size_t)tid * 4;

    // stage half 0 (rows 0..31), then immediately re-issue those regs for tile t+1
#pragma unroll
    for (int i = 0; i < 4; ++i) {
      const int f4 = tid + i * 512;
      const int r = f4 >> 6, hq = (f4 & 63) * 4;
      half4_t hv;
      hv[0] = (_Float16)ld[i][0]; hv[1] = (_Float16)ld[i][1];
      hv[2] = (_Float16)ld[i][2]; hv[3] = (_Float16)ld[i][3];
      *(half4_t*)&As[p][r][hq] = hv;
    }
    if (pf) {
#pragma unroll
      for (int i = 0; i < 4; ++i) ld[i] = *(const f32x4*)(srcN + i * 2048);
    }
    // stage half 1 (rows 32..63), re-issue
#pragma unroll
    for (int i = 4; i < 8; ++i) {
      const int f4 = tid + i * 512;
      const int r = f4 >> 6, hq = (f4 & 63) * 4;
      half4_t hv;
      hv[0] = (_Float16)ld[i][0]; hv[1] = (_Float16)ld[i][1];
      hv[2] = (_Float16)ld[i][2]; hv[3] = (_Float16)ld[i][3];
      *(half4_t*)&As[p][r][hq] = hv;
    }
    if (pf) {
#pragma unroll
      for (int i = 4; i < 8; ++i) ld[i] = *(const f32x4*)(srcN + i * 2048);
    }
    lds_barrier();   // As[p] visible; tile-t+1 loads remain in flight

    // ---- MFMA: proj tile [64 x 32(this wave)] -> score partials (bias in acc init)
#pragma unroll
    for (int rf = 0; rf < 4; ++rf) {
      f32x4 d0 = {bv0, bv0, bv0, bv0}, d1 = {bv1, bv1, bv1, bv1};
#pragma unroll
      for (int ks = 0; ks < 8; ++ks) {
        half8 a = *(const half8*)&As[p][rf * 16 + nlo][ks * 32 + khi];
        d0 = __builtin_amdgcn_mfma_f32_16x16x32_f16(a, wf[0][ks], d0, 0, 0, 0);
        d1 = __builtin_amdgcn_mfma_f32_16x16x32_f16(a, wf[1][ks], d1, 0, 0, 0);
      }
      f32x4 s4;
#pragma unroll
      for (int i = 0; i < 4; ++i)
        s4[i] = tanh_fast(d0[i]) * vv0 + tanh_fast(d1[i]) * vv1;
      // reduce over the 16 cols (nlo) via DPP row_shl adds: lane nlo==0 gets the sum
#pragma unroll
      for (int i = 0; i < 4; ++i) s4[i] = row_reduce16(s4[i]);
      if (nlo == 0) {  // lanes 0,16,32,48: rows rf*16 + g*4 + i
#pragma unroll
        for (int i = 0; i < 4; ++i) spartT[rf * 16 + g * 4 + i][wave] = s4[i];
      }
    }
    lds_barrier();   // spartT visible; prefetch still in flight

    // ---- weights + context: wave handles rows [8w, 8w+8); redundant weights on all lanes
#pragma unroll
    for (int rr = 0; rr < 8; ++rr) {
      const int r = wave * 8 + rr;
      const f32x4 q0 = *(const f32x4*)&spartT[r][0];   // broadcast reads (free)
      const f32x4 q1 = *(const f32x4*)&spartT[r][4];
      const float u = __expf(q0[0] + q0[1] + q0[2] + q0[3] + q1[0] + q1[1] + q1[2] + q1[3]);
      l_acc += u;
      half4_t a = *(const half4_t*)&As[p][r][lane * 4];
      c0 += u * (float)a[0];
      c1 += u * (float)a[1];
      c2 += u * (float)a[2];
      c3 += u * (float)a[3];
    }
    // no barrier: stage(t+1) writes As[p^1] (disjoint); spartT rewritten only after barrier1(t+1)
  }

  // ---- epilogue: merge 8 waves
  {
    f32x4 cv; cv[0] = c0; cv[1] = c1; cv[2] = c2; cv[3] = c3;
    *(f32x4*)&cpart[wave][lane * 4] = cv;
  }
  if (lane == 0) lArr[wave] = l_acc;
  __syncthreads();
  if (tid < H_SZ) {
    float s = 0.f;
#pragma unroll
    for (int w = 0; w < 8; ++w) s += cpart[w][tid];
    pc[(size_t)blockIdx.x * H_SZ + tid] = s;
  }
  if (tid == 0) {
    float L = 0.f;
#pragma unroll
    for (int w = 0; w < 8; ++w) L += lArr[w];
    pl[blockIdx.x] = L;
  }
}

// ---------------- kernel 2: merge 8 chunk partials per batch (plain sums) ----------------
__global__ __launch_bounds__(256) void combine_kernel(const float* __restrict__ pc,
                                                      const float* __restrict__ pl,
                                                      float* __restrict__ out) {
  const int b = blockIdx.x, h = threadIdx.x;
  float L = 0.f, s = 0.f;
#pragma unroll
  for (int j = 0; j < CHUNKS; ++j) {
    L += pl[b * CHUNKS + j];
    s += pc[(size_t)(b * CHUNKS + j) * H_SZ + h];
  }
  out[b * H_SZ + h] = s / L;
}

extern "C" void kernel_launch(void* const* d_in, const int* in_sizes, int n_in,
                              void* d_out, int out_size, void* d_ws, size_t ws_size,
                              hipStream_t stream) {
  const float* enc = (const float*)d_in[0];  // [64,4096,256]
  const float* fh  = (const float*)d_in[1];  // [64,256]
  const float* W1  = (const float*)d_in[2];  // [256,256]
  const float* W2  = (const float*)d_in[3];  // [256,256]
  const float* v   = (const float*)d_in[4];  // [256]
  float* out = (float*)d_out;                // [64,256]

  float* ws   = (float*)d_ws;
  float* bias = ws;                          // 64*256
  float* pc   = ws + B_SZ * H_SZ;            // 512*256
  float* pl   = pc + B_SZ * CHUNKS * H_SZ;   // 512

  bias_kernel<<<B_SZ, H_SZ, 0, stream>>>(fh, W2, bias);
  fused_kernel<<<B_SZ * CHUNKS, 512, 0, stream>>>(enc, W1, v, bias, pc, pl);
  combine_kernel<<<B_SZ, H_SZ, 0, stream>>>(pc, pl, out);
}

// Round 7
// 87.966 us; speedup vs baseline: 6.5658x; 1.0305x over previous
//
#include <hip/hip_runtime.h>

typedef _Float16 half8  __attribute__((ext_vector_type(8)));
typedef _Float16 half4_t __attribute__((ext_vector_type(4)));
typedef float    f32x4  __attribute__((ext_vector_type(4)));

#define B_SZ    64
#define S_SZ    4096
#define H_SZ    256
#define CHUNKS  8
#define SCHUNK  512
#define TILE_R  32
#define NTILES  (SCHUNK / TILE_R)   // 16
#define PAD_H   264                 // row stride 132 words

__device__ __forceinline__ float tanh_fast(float x) {
  // 1 - 2/(e^{2x}+1); rcpf: +inf -> 1, -inf -> -1, no NaN
  return 1.f - 2.f * __builtin_amdgcn_rcpf(__expf(2.f * x) + 1.f);
}

// LDS-visibility barrier that does NOT drain vmcnt: global prefetch stays in flight.
__device__ __forceinline__ void lds_barrier() {
  asm volatile("s_waitcnt lgkmcnt(0)" ::: "memory");
  __builtin_amdgcn_s_barrier();
}

// After shl8,shl4,shl2,shl1 (bound_ctrl zero-fill): lane 0 of each 16-lane row = row sum.
template<int CTRL>
__device__ __forceinline__ float dpp_add_shl(float x) {
  int s = __builtin_amdgcn_update_dpp(0, __builtin_bit_cast(int, x), CTRL, 0xf, 0xf, true);
  return x + __builtin_bit_cast(float, s);
}
__device__ __forceinline__ float row_reduce16(float x) {
  x = dpp_add_shl<0x108>(x);  // row_shl:8
  x = dpp_add_shl<0x104>(x);  // row_shl:4
  x = dpp_add_shl<0x102>(x);  // row_shl:2
  x = dpp_add_shl<0x101>(x);  // row_shl:1
  return x;
}

// ---------------- kernel 0: bias[b][k] = sum_h final_h[b][h] * W2[k][h] ----------------
__global__ __launch_bounds__(256) void bias_kernel(const float* __restrict__ fh,
                                                   const float* __restrict__ W2,
                                                   float* __restrict__ bias) {
  const int b = blockIdx.x, k = threadIdx.x;
  __shared__ float fsh[H_SZ];
  fsh[k] = fh[b * H_SZ + k];
  __syncthreads();
  const float* wrow = W2 + (size_t)k * H_SZ;
  float s = 0.f;
#pragma unroll 4
  for (int h = 0; h < H_SZ; h += 4) {
    f32x4 w = *(const f32x4*)(wrow + h);
    s += w[0] * fsh[h] + w[1] * fsh[h + 1] + w[2] * fsh[h + 2] + w[3] * fsh[h + 3];
  }
  bias[b * H_SZ + k] = s;
}

// ---------------- kernel 1: fused; 1 barrier/tile; context deferred one tile ------------
// grid 512 = 64 b * 8 chunks; block 512 = 8 waves. Wave w owns proj cols [32w, 32w+32).
// Pipeline per t: stage(t)->As[t%3] | barrier | MFMA+score(t)->spartT[t&1] || context(t-1).
// Hazards: As[t%3] last read by context(t-3) (>=2 barriers ago); spartT[t&1] last read by
// context(t-2) (1 barrier ago); context(t-1) reads spartT[(t-1)&1] written 1 barrier ago.
__global__ __launch_bounds__(512, 2) void fused_kernel(const float* __restrict__ enc,
                                                       const float* __restrict__ W1,
                                                       const float* __restrict__ v,
                                                       const float* __restrict__ bias,
                                                       float* __restrict__ pc,   // [512][256]
                                                       float* __restrict__ pl) { // [512]
  __shared__ _Float16 As[3][TILE_R][PAD_H] __attribute__((aligned(16)));  // 49.5 KB
  __shared__ float spartT[2][TILE_R][12];  // score partials, double-buffered
  __shared__ float cpart[8][H_SZ];         // epilogue context merge
  __shared__ float lArr[8];

  const int tid  = threadIdx.x;
  const int wave = tid >> 6;
  const int lane = tid & 63;
  const int nlo  = lane & 15;
  const int g    = lane >> 4;
  const int khi  = g * 8;
  const int b     = blockIdx.x >> 3;
  const int chunk = blockIdx.x & 7;
  const size_t encBase = ((size_t)b * S_SZ + (size_t)chunk * SCHUNK) * H_SZ;

  // prologue: issue tile-0 loads FIRST (critical stream)
  f32x4 ld[4];
  {
    const float* src = enc + encBase + (size_t)tid * 4;
#pragma unroll
    for (int i = 0; i < 4; ++i) ld[i] = *(const f32x4*)(src + i * 2048);
  }

  // ---- W1 fragments in registers: B[k=h][n=col]; lane l holds col wave*32+cf*16+nlo
  half8 wf[2][8];
#pragma unroll
  for (int cf = 0; cf < 2; ++cf) {
    const int n = wave * 32 + cf * 16 + nlo;
    const float* wrow = W1 + (size_t)n * H_SZ + khi;
#pragma unroll
    for (int ks = 0; ks < 8; ++ks) {
      f32x4 w0 = *(const f32x4*)(wrow + ks * 32);
      f32x4 w1 = *(const f32x4*)(wrow + ks * 32 + 4);
      half8 h;
#pragma unroll
      for (int j = 0; j < 4; ++j) { h[j] = (_Float16)w0[j]; h[4 + j] = (_Float16)w1[j]; }
      wf[cf][ks] = h;
    }
  }
  const int n0c = wave * 32 + nlo;
  const float vv0 = v[n0c],               vv1 = v[n0c + 16];
  const float bv0 = bias[b * H_SZ + n0c], bv1 = bias[b * H_SZ + n0c + 16];

  float l_acc = 0.f;
  float c0 = 0.f, c1 = 0.f, c2 = 0.f, c3 = 0.f;  // context h-slice: h = 4*lane..+3

  int p = 0;        // t % 3
  int pm1 = 2;      // (t-1) % 3

#pragma unroll 1
  for (int t = 0; t < NTILES; ++t) {
    const bool pf = (t < NTILES - 1);
    const float* srcN = enc + encBase + (size_t)(t + 1) * TILE_R * H_SZ + (size_t)tid * 4;

    // stage(t): consume ld -> As[p]; immediately re-issue for tile t+1
#pragma unroll
    for (int i = 0; i < 4; ++i) {
      const int f4 = tid + i * 512;
      const int r = f4 >> 6, hq = (f4 & 63) * 4;
      half4_t hv;
      hv[0] = (_Float16)ld[i][0]; hv[1] = (_Float16)ld[i][1];
      hv[2] = (_Float16)ld[i][2]; hv[3] = (_Float16)ld[i][3];
      *(half4_t*)&As[p][r][hq] = hv;
    }
    if (pf) {
#pragma unroll
      for (int i = 0; i < 4; ++i) ld[i] = *(const f32x4*)(srcN + i * 2048);
    }
    lds_barrier();   // As[p] + spartT[(t-1)&1] visible; prefetch stays in flight

    // ---- MFMA+score(t): proj tile [32 x 32(this wave)] (bias in acc init)
#pragma unroll
    for (int rf = 0; rf < 2; ++rf) {
      f32x4 d0 = {bv0, bv0, bv0, bv0}, d1 = {bv1, bv1, bv1, bv1};
#pragma unroll
      for (int ks = 0; ks < 8; ++ks) {
        half8 a = *(const half8*)&As[p][rf * 16 + nlo][ks * 32 + khi];
        d0 = __builtin_amdgcn_mfma_f32_16x16x32_f16(a, wf[0][ks], d0, 0, 0, 0);
        d1 = __builtin_amdgcn_mfma_f32_16x16x32_f16(a, wf[1][ks], d1, 0, 0, 0);
      }
      f32x4 s4;
#pragma unroll
      for (int i = 0; i < 4; ++i)
        s4[i] = tanh_fast(d0[i]) * vv0 + tanh_fast(d1[i]) * vv1;
#pragma unroll
      for (int i = 0; i < 4; ++i) s4[i] = row_reduce16(s4[i]);
      if (nlo == 0) {  // lanes 0,16,32,48: rows rf*16 + g*4 + i
#pragma unroll
        for (int i = 0; i < 4; ++i) spartT[t & 1][rf * 16 + g * 4 + i][wave] = s4[i];
      }
    }

    // ---- context(t-1): rows [4w, 4w+4) of As[pm1]; spartT[(t-1)&1] (both 1+ barrier old)
    if (t > 0) {
#pragma unroll
      for (int rr = 0; rr < 4; ++rr) {
        const int r = wave * 4 + rr;
        const f32x4 q0 = *(const f32x4*)&spartT[(t - 1) & 1][r][0];  // broadcast reads
        const f32x4 q1 = *(const f32x4*)&spartT[(t - 1) & 1][r][4];
        const float u = __expf(q0[0] + q0[1] + q0[2] + q0[3] + q1[0] + q1[1] + q1[2] + q1[3]);
        l_acc += u;
        half4_t a = *(const half4_t*)&As[pm1][r][lane * 4];
        c0 += u * (float)a[0];
        c1 += u * (float)a[1];
        c2 += u * (float)a[2];
        c3 += u * (float)a[3];
      }
    }
    pm1 = p;
    p = (p == 2) ? 0 : p + 1;
  }

  // ---- drain: context(NTILES-1)
  lds_barrier();
  {
    const int tl = (NTILES - 1) & 1;
#pragma unroll
    for (int rr = 0; rr < 4; ++rr) {
      const int r = wave * 4 + rr;
      const f32x4 q0 = *(const f32x4*)&spartT[tl][r][0];
      const f32x4 q1 = *(const f32x4*)&spartT[tl][r][4];
      const float u = __expf(q0[0] + q0[1] + q0[2] + q0[3] + q1[0] + q1[1] + q1[2] + q1[3]);
      l_acc += u;
      half4_t a = *(const half4_t*)&As[pm1][r][lane * 4];
      c0 += u * (float)a[0];
      c1 += u * (float)a[1];
      c2 += u * (float)a[2];
      c3 += u * (float)a[3];
    }
  }

  // ---- epilogue: merge 8 waves
  {
    f32x4 cv; cv[0] = c0; cv[1] = c1; cv[2] = c2; cv[3] = c3;
    *(f32x4*)&cpart[wave][lane * 4] = cv;
  }
  if (lane == 0) lArr[wave] = l_acc;
  __syncthreads();
  if (tid < H_SZ) {
    float s = 0.f;
#pragma unroll
    for (int w = 0; w < 8; ++w) s += cpart[w][tid];
    pc[(size_t)blockIdx.x * H_SZ + tid] = s;
  }
  if (tid == 0) {
    float L = 0.f;
#pragma unroll
    for (int w = 0; w < 8; ++w) L += lArr[w];
    pl[blockIdx.x] = L;
  }
}

// ---------------- kernel 2: merge 8 chunk partials per batch (plain sums) ----------------
__global__ __launch_bounds__(256) void combine_kernel(const float* __restrict__ pc,
                                                      const float* __restrict__ pl,
                                                      float* __restrict__ out) {
  const int b = blockIdx.x, h = threadIdx.x;
  float L = 0.f, s = 0.f;
#pragma unroll
  for (int j = 0; j < CHUNKS; ++j) {
    L += pl[b * CHUNKS + j];
    s += pc[(size_t)(b * CHUNKS + j) * H_SZ + h];
  }
  out[b * H_SZ + h] = s / L;
}

extern "C" void kernel_launch(void* const* d_in, const int* in_sizes, int n_in,
                              void* d_out, int out_size, void* d_ws, size_t ws_size,
                              hipStream_t stream) {
  const float* enc = (const float*)d_in[0];  // [64,4096,256]
  const float* fh  = (const float*)d_in[1];  // [64,256]
  const float* W1  = (const float*)d_in[2];  // [256,256]
  const float* W2  = (const float*)d_in[3];  // [256,256]
  const float* v   = (const float*)d_in[4];  // [256]
  float* out = (float*)d_out;                // [64,256]

  float* ws   = (float*)d_ws;
  float* bias = ws;                          // 64*256
  float* pc   = ws + B_SZ * H_SZ;            // 512*256
  float* pl   = pc + B_SZ * CHUNKS * H_SZ;   // 512

  bias_kernel<<<B_SZ, H_SZ, 0, stream>>>(fh, W2, bias);
  fused_kernel<<<B_SZ * CHUNKS, 512, 0, stream>>>(enc, W1, v, bias, pc, pl);
  combine_kernel<<<B_SZ, H_SZ, 0, stream>>>(pc, pl, out);
}

// Round 8
// 86.673 us; speedup vs baseline: 6.6638x; 1.0149x over previous
//
#include <hip/hip_runtime.h>

typedef _Float16 half8  __attribute__((ext_vector_type(8)));
typedef _Float16 half4_t __attribute__((ext_vector_type(4)));
typedef float    f32x4  __attribute__((ext_vector_type(4)));

#define B_SZ    64
#define S_SZ    4096
#define H_SZ    256
#define CHUNKS  8
#define SCHUNK  512
#define TILE_R  32
#define NTILES  (SCHUNK / TILE_R)   // 16
#define PAD_H   264                 // row stride 132 words

__device__ __forceinline__ float tanh_fast(float x) {
  // 1 - 2/(e^{2x}+1); rcpf: +inf -> 1, -inf -> -1, no NaN
  return 1.f - 2.f * __builtin_amdgcn_rcpf(__expf(2.f * x) + 1.f);
}

// LDS-visibility barrier that does NOT drain vmcnt: global prefetch stays in flight.
__device__ __forceinline__ void lds_barrier() {
  asm volatile("s_waitcnt lgkmcnt(0)" ::: "memory");
  __builtin_amdgcn_s_barrier();
}

// After shl8,shl4,shl2,shl1 (bound_ctrl zero-fill): lane 0 of each 16-lane row = row sum.
template<int CTRL>
__device__ __forceinline__ float dpp_add_shl(float x) {
  int s = __builtin_amdgcn_update_dpp(0, __builtin_bit_cast(int, x), CTRL, 0xf, 0xf, true);
  return x + __builtin_bit_cast(float, s);
}
__device__ __forceinline__ float row_reduce16(float x) {
  x = dpp_add_shl<0x108>(x);  // row_shl:8
  x = dpp_add_shl<0x104>(x);  // row_shl:4
  x = dpp_add_shl<0x102>(x);  // row_shl:2
  x = dpp_add_shl<0x101>(x);  // row_shl:1
  return x;
}

// ---------------- kernel 0: bias[b][k] = sum_h final_h[b][h] * W2[k][h] ----------------
__global__ __launch_bounds__(256) void bias_kernel(const float* __restrict__ fh,
                                                   const float* __restrict__ W2,
                                                   float* __restrict__ bias) {
  const int b = blockIdx.x, k = threadIdx.x;
  __shared__ float fsh[H_SZ];
  fsh[k] = fh[b * H_SZ + k];
  __syncthreads();
  const float* wrow = W2 + (size_t)k * H_SZ;
  float s = 0.f;
#pragma unroll 4
  for (int h = 0; h < H_SZ; h += 4) {
    f32x4 w = *(const f32x4*)(wrow + h);
    s += w[0] * fsh[h] + w[1] * fsh[h + 1] + w[2] * fsh[h + 2] + w[3] * fsh[h + 3];
  }
  bias[b * H_SZ + k] = s;
}

// ---------------- kernel 1: fused; 1 barrier/tile; 2-deep register prefetch -------------
// grid 512 = 64 b * 8 chunks; block 512 = 8 waves. Wave w owns proj cols [32w, 32w+32).
// Per t: stage(t)<-ldbuf[t&1]; reissue ldbuf[t&1]<-loads(t+2); barrier;
//        MFMA+score(t)->spartT[t&1] ; context(t-1) from As[pm1]+spartT[(t-1)&1].
// Two tiles always in HBM flight per wave (8 loads outstanding).
__global__ __launch_bounds__(512, 2) void fused_kernel(const float* __restrict__ enc,
                                                       const float* __restrict__ W1,
                                                       const float* __restrict__ v,
                                                       const float* __restrict__ bias,
                                                       float* __restrict__ pc,   // [512][256]
                                                       float* __restrict__ pl) { // [512]
  __shared__ _Float16 As[3][TILE_R][PAD_H] __attribute__((aligned(16)));  // 49.5 KB
  __shared__ float spartT[2][TILE_R][12];  // score partials, double-buffered
  __shared__ float cpart[8][H_SZ];         // epilogue context merge
  __shared__ float lArr[8];

  const int tid  = threadIdx.x;
  const int wave = tid >> 6;
  const int lane = tid & 63;
  const int nlo  = lane & 15;
  const int g    = lane >> 4;
  const int khi  = g * 8;
  const int b     = blockIdx.x >> 3;
  const int chunk = blockIdx.x & 7;
  const size_t encBase = ((size_t)b * S_SZ + (size_t)chunk * SCHUNK) * H_SZ;
  const float* src0 = enc + encBase + (size_t)tid * 4;

  // prologue: issue tile-0 loads FIRST (critical stream)
  f32x4 ldA[4], ldB[4];
#pragma unroll
  for (int i = 0; i < 4; ++i) ldA[i] = *(const f32x4*)(src0 + i * 2048);

  // ---- W1 fragments in registers: B[k=h][n=col]; lane l holds col wave*32+cf*16+nlo
  half8 wf[2][8];
#pragma unroll
  for (int cf = 0; cf < 2; ++cf) {
    const int n = wave * 32 + cf * 16 + nlo;
    const float* wrow = W1 + (size_t)n * H_SZ + khi;
#pragma unroll
    for (int ks = 0; ks < 8; ++ks) {
      f32x4 w0 = *(const f32x4*)(wrow + ks * 32);
      f32x4 w1 = *(const f32x4*)(wrow + ks * 32 + 4);
      half8 h;
#pragma unroll
      for (int j = 0; j < 4; ++j) { h[j] = (_Float16)w0[j]; h[4 + j] = (_Float16)w1[j]; }
      wf[cf][ks] = h;
    }
  }
  // issue tile-1 loads (second buffer) right after W1 setup
#pragma unroll
  for (int i = 0; i < 4; ++i) ldB[i] = *(const f32x4*)(src0 + TILE_R * H_SZ + i * 2048);

  const int n0c = wave * 32 + nlo;
  const float vv0 = v[n0c],               vv1 = v[n0c + 16];
  const float bv0 = bias[b * H_SZ + n0c], bv1 = bias[b * H_SZ + n0c + 16];

  float l_acc = 0.f;
  float c0 = 0.f, c1 = 0.f, c2 = 0.f, c3 = 0.f;  // context h-slice: h = 4*lane..+3

  int p = 0;        // t % 3
  int pm1 = 2;      // (t-1) % 3

  // one tile-iteration; ld is the buffer holding tile t, re-issued for tile t+2
  auto tile_iter = [&](int t, f32x4 (&ld)[4]) {
    // stage(t): consume ld -> As[p]
#pragma unroll
    for (int i = 0; i < 4; ++i) {
      const int f4 = tid + i * 512;
      const int r = f4 >> 6, hq = (f4 & 63) * 4;
      half4_t hv;
      hv[0] = (_Float16)ld[i][0]; hv[1] = (_Float16)ld[i][1];
      hv[2] = (_Float16)ld[i][2]; hv[3] = (_Float16)ld[i][3];
      *(half4_t*)&As[p][r][hq] = hv;
    }
    // re-issue this buffer for tile t+2 (2 tiles always in flight)
    if (t + 2 < NTILES) {
      const float* srcN = src0 + (size_t)(t + 2) * TILE_R * H_SZ;
#pragma unroll
      for (int i = 0; i < 4; ++i) ld[i] = *(const f32x4*)(srcN + i * 2048);
    }
    lds_barrier();   // As[p] + spartT[(t-1)&1] visible; prefetch stays in flight

    // ---- MFMA+score(t): proj tile [32 x 32(this wave)] (bias in acc init)
#pragma unroll
    for (int rf = 0; rf < 2; ++rf) {
      f32x4 d0 = {bv0, bv0, bv0, bv0}, d1 = {bv1, bv1, bv1, bv1};
#pragma unroll
      for (int ks = 0; ks < 8; ++ks) {
        half8 a = *(const half8*)&As[p][rf * 16 + nlo][ks * 32 + khi];
        d0 = __builtin_amdgcn_mfma_f32_16x16x32_f16(a, wf[0][ks], d0, 0, 0, 0);
        d1 = __builtin_amdgcn_mfma_f32_16x16x32_f16(a, wf[1][ks], d1, 0, 0, 0);
      }
      f32x4 s4;
#pragma unroll
      for (int i = 0; i < 4; ++i)
        s4[i] = tanh_fast(d0[i]) * vv0 + tanh_fast(d1[i]) * vv1;
#pragma unroll
      for (int i = 0; i < 4; ++i) s4[i] = row_reduce16(s4[i]);
      if (nlo == 0) {  // lanes 0,16,32,48: rows rf*16 + g*4 + i
#pragma unroll
        for (int i = 0; i < 4; ++i) spartT[t & 1][rf * 16 + g * 4 + i][wave] = s4[i];
      }
    }

    // ---- context(t-1): rows [4w, 4w+4) of As[pm1]; spartT[(t-1)&1] (1 barrier old)
    if (t > 0) {
#pragma unroll
      for (int rr = 0; rr < 4; ++rr) {
        const int r = wave * 4 + rr;
        const f32x4 q0 = *(const f32x4*)&spartT[(t - 1) & 1][r][0];  // broadcast reads
        const f32x4 q1 = *(const f32x4*)&spartT[(t - 1) & 1][r][4];
        const float u = __expf(q0[0] + q0[1] + q0[2] + q0[3] + q1[0] + q1[1] + q1[2] + q1[3]);
        l_acc += u;
        half4_t a = *(const half4_t*)&As[pm1][r][lane * 4];
        c0 += u * (float)a[0];
        c1 += u * (float)a[1];
        c2 += u * (float)a[2];
        c3 += u * (float)a[3];
      }
    }
    pm1 = p;
    p = (p == 2) ? 0 : p + 1;
  };

#pragma unroll 1
  for (int t2 = 0; t2 < NTILES; t2 += 2) {
    tile_iter(t2,     ldA);
    tile_iter(t2 + 1, ldB);
  }

  // ---- drain: context(NTILES-1)
  lds_barrier();
  {
    const int tl = (NTILES - 1) & 1;
#pragma unroll
    for (int rr = 0; rr < 4; ++rr) {
      const int r = wave * 4 + rr;
      const f32x4 q0 = *(const f32x4*)&spartT[tl][r][0];
      const f32x4 q1 = *(const f32x4*)&spartT[tl][r][4];
      const float u = __expf(q0[0] + q0[1] + q0[2] + q0[3] + q1[0] + q1[1] + q1[2] + q1[3]);
      l_acc += u;
      half4_t a = *(const half4_t*)&As[pm1][r][lane * 4];
      c0 += u * (float)a[0];
      c1 += u * (float)a[1];
      c2 += u * (float)a[2];
      c3 += u * (float)a[3];
    }
  }

  // ---- epilogue: merge 8 waves
  {
    f32x4 cv; cv[0] = c0; cv[1] = c1; cv[2] = c2; cv[3] = c3;
    *(f32x4*)&cpart[wave][lane * 4] = cv;
  }
  if (lane == 0) lArr[wave] = l_acc;
  __syncthreads();
  if (tid < H_SZ) {
    float s = 0.f;
#pragma unroll
    for (int w = 0; w < 8; ++w) s += cpart[w][tid];
    pc[(size_t)blockIdx.x * H_SZ + tid] = s;
  }
  if (tid == 0) {
    float L = 0.f;
#pragma unroll
    for (int w = 0; w < 8; ++w) L += lArr[w];
    pl[blockIdx.x] = L;
  }
}

// ---------------- kernel 2: merge 8 chunk partials per batch (plain sums) ----------------
__global__ __launch_bounds__(256) void combine_kernel(const float* __restrict__ pc,
                                                      const float* __restrict__ pl,
                                                      float* __restrict__ out) {
  const int b = blockIdx.x, h = threadIdx.x;
  float L = 0.f, s = 0.f;
#pragma unroll
  for (int j = 0; j < CHUNKS; ++j) {
    L += pl[b * CHUNKS + j];
    s += pc[(size_t)(b * CHUNKS + j) * H_SZ + h];
  }
  out[b * H_SZ + h] = s / L;
}

extern "C" void kernel_launch(void* const* d_in, const int* in_sizes, int n_in,
                              void* d_out, int out_size, void* d_ws, size_t ws_size,
                              hipStream_t stream) {
  const float* enc = (const float*)d_in[0];  // [64,4096,256]
  const float* fh  = (const float*)d_in[1];  // [64,256]
  const float* W1  = (const float*)d_in[2];  // [256,256]
  const float* W2  = (const float*)d_in[3];  // [256,256]
  const float* v   = (const float*)d_in[4];  // [256]
  float* out = (float*)d_out;                // [64,256]

  float* ws   = (float*)d_ws;
  float* bias = ws;                          // 64*256
  float* pc   = ws + B_SZ * H_SZ;            // 512*256
  float* pl   = pc + B_SZ * CHUNKS * H_SZ;   // 512

  bias_kernel<<<B_SZ, H_SZ, 0, stream>>>(fh, W2, bias);
  fused_kernel<<<B_SZ * CHUNKS, 512, 0, stream>>>(enc, W1, v, bias, pc, pl);
  combine_kernel<<<B_SZ, H_SZ, 0, stream>>>(pc, pl, out);
}